// Round 4
// baseline (460.745 us; speedup 1.0000x reference)
//
#include <hip/hip_runtime.h>

typedef __bf16 bf16;
typedef __bf16 bf16x4 __attribute__((ext_vector_type(4)));
typedef __bf16 bf16x8 __attribute__((ext_vector_type(8)));
typedef float f32x4 __attribute__((ext_vector_type(4)));

#define K_TOT 1024    // D_IN
#define N_TOT 512     // H1
#define T_SEQ 2048
#define NB 32
#define M_TILE 160    // max rows per gemm block (LDS/acc capacity)
#define MAX_J 13      // ceil(2048/160): worst-case initial tiles per sample
#define NBLK_TGT 256  // one block per CU -> single dispatch round

// ---------------------------------------------------------------------------
// async global->LDS, 16B per lane. LDS dest = wave-uniform base + lane*16.
// ---------------------------------------------------------------------------
__device__ __forceinline__ void async16(const void* g, void* l) {
    __builtin_amdgcn_global_load_lds(
        (const __attribute__((address_space(1))) unsigned int*)g,
        (__attribute__((address_space(3))) unsigned int*)l, 16, 0, 0);
}

// ---------------------------------------------------------------------------
// Kernel 0 (merged): W1 [1024,512] fp32 -> W1T [512,1024] bf16, AND (block 0)
// prep: fold layers 2+3 into v[], zero completion counters, and build a
// BALANCED block partition: sample b gets nb_b blocks (greedy, total = 256,
// minimizing max rows/block); block j of sample b covers a contiguous slice
// of its first L_b rows (<= 160 rows each). Rows at t >= L are dead work
// (masked out of the ref top-k) and are never fetched.
// tiles[0] = total blocks; tiles[1+i] = (b<<19) | (start<<8) | nrows.
// ---------------------------------------------------------------------------
__global__ __launch_bounds__(256) void transpose_prep(
        const float* __restrict__ W1, bf16* __restrict__ W1T,
        const float* __restrict__ W2, const float* __restrict__ b2,
        const float* __restrict__ W3, const float* __restrict__ b3,
        const int* __restrict__ seq_len,
        float* __restrict__ v, int* __restrict__ tiles, int* __restrict__ done) {
    __shared__ float tile[32][33];
    __shared__ int nb2[32], off2[32], Ls[32];
    const int t = threadIdx.x;
    const int k0 = blockIdx.x * 32;
    const int n0 = blockIdx.y * 32;
#pragma unroll
    for (int p = 0; p < 4; p++) {
        int kl = p * 8 + (t >> 5);
        int nl = t & 31;
        tile[kl][nl] = W1[(k0 + kl) * 512 + n0 + nl];
    }
    __syncthreads();
#pragma unroll
    for (int p = 0; p < 4; p++) {
        int nl = p * 8 + (t >> 5);
        int kl = t & 31;
        W1T[(n0 + nl) * 1024 + k0 + kl] = (bf16)tile[kl][nl];
    }

    if (blockIdx.x == 0 && blockIdx.y == 0) {   // block-uniform branch
        // v[h] = sum_c W2[h][c]*W3[c];  v[512] = b2.W3 + b3
        for (int h = t; h < 512; h += 256) {
            float s = 0.f;
#pragma unroll
            for (int c = 0; c < 32; c++) s += W2[h * 32 + c] * W3[c];
            v[h] = s;
        }
        if (t == 0) {
            float cc = b3[0];
            for (int c = 0; c < 32; c++) cc += b2[c] * W3[c];
            v[512] = cc;
        }
        if (t < 32) {
            int L = seq_len[t];
            Ls[t] = L;
            nb2[t] = (L + M_TILE - 1) / M_TILE;   // ensures rows/block <= 160
            done[t] = 0;                          // completion counters (rows)
        }
        __syncthreads();
        if (t == 0) {
            int tot = 0;
            for (int i = 0; i < 32; i++) tot += nb2[i];
            // greedy: add blocks to the sample with max rows/block until 256.
            // Monotone: nb only grows -> rows/block only shrinks (stays <=160).
            while (tot < NBLK_TGT) {
                int best = -1, bestr = 1;         // never split below 2 rows
                for (int i = 0; i < 32; i++) {
                    int r = (Ls[i] + nb2[i] - 1) / nb2[i];
                    if (r > bestr && nb2[i] < Ls[i]) { bestr = r; best = i; }
                }
                if (best < 0) break;
                nb2[best]++; tot++;
            }
            int a = 0;
            for (int i = 0; i < 32; i++) { off2[i] = a; a += nb2[i]; }
            tiles[0] = a;
        }
        __syncthreads();
        for (int idx = t; idx < 32 * 256; idx += 256) {
            int b = idx >> 8, j = idx & 255;
            int nb = nb2[b];
            if (j < nb) {
                int L = Ls[b];
                int q = L / nb, r = L % nb;       // balanced split, all >= 1
                int start = j * q + (j < r ? j : r);
                int nrows = q + (j < r ? 1 : 0);
                tiles[1 + off2[b] + j] = (b << 19) | (start << 8) | nrows;
            }
        }
    }
}

// ---------------------------------------------------------------------------
// Kernel 1 (fused gemm + MLP epilogue + per-sample top-k):
// per block: mrows (<=160) rows x full N=512; logits = sigmoid(sum relu*v+c).
// LDS 148 KB: A single-buffered 20 KB (next A rides in VGPRs through MFMA)
// + B double-buffered 2x64 KB via global_load_lds.
// Rows >= mrows: A-load & store predicated off (no fetch); MFMA runs on stale
// LDS for those rows (row-independent garbage, masked at store).
// Last block of each sample (row-count protocol) runs its top-k mean inline.
// ---------------------------------------------------------------------------
__device__ __forceinline__ int sw_idx(int row, int e) {  // elem idx into [row][64]
    return row * 64 + (((e >> 3) ^ (row & 7)) << 3) + (e & 7);
}

__global__ __launch_bounds__(512, 2) void gemm_fused(const float* __restrict__ A,
                                                     const bf16* __restrict__ W1T,
                                                     const float* __restrict__ b1,
                                                     const float* __restrict__ v,
                                                     const int* __restrict__ tiles,
                                                     const int* __restrict__ seq_len,
                                                     int* __restrict__ done,
                                                     float* __restrict__ logits,
                                                     float* __restrict__ out) {
    // 160*64 (A) + 2 * 512*64 (B) bf16 = 148 KB
    __shared__ bf16 smem[M_TILE * 64 + 2 * N_TOT * 64];
    bf16* As = smem;
    bf16* Bs0 = smem + M_TILE * 64;
    bf16* Bs1 = Bs0 + N_TOT * 64;

    const int nact = tiles[0];
    if ((int)blockIdx.x >= nact) return;         // dead slot
    const int w = tiles[1 + blockIdx.x];
    const int bsmp = w >> 19;                    // owning sample
    const int start = (w >> 8) & 0x7FF;          // first row within sample
    const int mrows = w & 0xFF;                  // live rows this block (<=160)
    const int m0 = bsmp * T_SEQ + start;         // first global row

    const int t = threadIdx.x;
    const int wave = t >> 6, lane = t & 63;
    const int q = lane >> 4, l15 = lane & 15;
    const int wm = wave >> 2, wn = wave & 3;     // 2 x 4 wave grid; wm tile 80 rows

    // A staging: thread t handles float4 col c16 = t&15 of rows r0+p*32.
    // 16 lanes cover one row's 64-float K-chunk = 256B contiguous runs.
    const int c16 = t & 15, r0 = t >> 4;
    const float* agp[5];
#pragma unroll
    for (int p = 0; p < 5; p++)
        agp[p] = A + (size_t)(m0 + r0 + p * 32) * K_TOT + c16 * 4;  // deref'd only if live

    // B async staging: lane -> n-row wave*64 + (lane>>3), global 16B chunk
    // XOR-permuted so linear LDS (base + lane*16) ends up swizzled.
    const int bl_row = wave * 64 + (lane >> 3);
    const int bl_chunk = (lane & 7) ^ ((lane >> 3) & 7);
    const bf16* bgp = W1T + (size_t)bl_row * K_TOT + bl_chunk * 8;

    f32x4 acc[5][8] = {};
    float4 av[5];

    auto loadA = [&](int k0) {
#pragma unroll
        for (int p = 0; p < 5; p++)
            if (r0 + p * 32 < mrows) av[p] = *(const float4*)(agp[p] + k0);
    };
    auto asyncB = [&](int k0, bf16* bs) {
#pragma unroll
        for (int j = 0; j < 8; j++)
            async16(bgp + k0 + (size_t)j * 8 * K_TOT, bs + (wave * 64 + j * 8) * 64);
    };
    auto writeA = [&]() {
#pragma unroll
        for (int p = 0; p < 5; p++) {
            if (r0 + p * 32 >= mrows) continue;
            bf16x4 wv;
            wv[0] = (bf16)av[p].x; wv[1] = (bf16)av[p].y;
            wv[2] = (bf16)av[p].z; wv[3] = (bf16)av[p].w;
            int row = r0 + p * 32;
            int chunk = c16 >> 1;                 // global 8-elem chunk
            int idx = row * 64 + ((chunk ^ (row & 7)) << 3) + (c16 & 1) * 4;
            *(bf16x4*)(&As[idx]) = wv;
        }
    };
    auto mfma_phase = [&](const bf16* bs) {
#pragma unroll
        for (int kk = 0; kk < 64; kk += 32) {
            const int e = kk + q * 8;
            bf16x8 af[5];
#pragma unroll
            for (int mi = 0; mi < 5; mi++)
                af[mi] = *(const bf16x8*)(&As[sw_idx(wm * 80 + mi * 16 + l15, e)]);
#pragma unroll
            for (int nh = 0; nh < 8; nh += 4) {   // ni-halves: caps VGPR pressure
                bf16x8 bfv[4];
#pragma unroll
                for (int ni = 0; ni < 4; ni++)
                    bfv[ni] = *(const bf16x8*)(&bs[sw_idx(wn * 128 + (nh + ni) * 16 + l15, e)]);
#pragma unroll
                for (int mi = 0; mi < 5; mi++)
#pragma unroll
                    for (int ni = 0; ni < 4; ni++)
                        acc[mi][nh + ni] = __builtin_amdgcn_mfma_f32_16x16x32_bf16(
                            af[mi], bfv[ni], acc[mi][nh + ni], 0, 0, 0);
            }
        }
    };

    // ---- preload k=0 ----
    loadA(0);
    asyncB(0, Bs0);
    writeA();           // compiler: vmcnt -> waits A only, B stays in flight
    __syncthreads();    // drains B(0); A(0) visible

#pragma unroll 1
    for (int k = 0; k < 16; k++) {
        bf16* bcur = (k & 1) ? Bs1 : Bs0;
        bf16* bnxt = (k & 1) ? Bs0 : Bs1;
        if (k < 15) {
            loadA((k + 1) * 64);        // A(k+1) -> VGPR (overlaps MFMA below)
            asyncB((k + 1) * 64, bnxt); // B(k+1) -> LDS async
        }
        mfma_phase(bcur);               // covers load latency
        __syncthreads();                // waves done reading As/B(k); drains B(k+1)
        if (k < 15) {
            writeA();                   // overwrite single A buffer with A(k+1)
            __syncthreads();            // A(k+1) visible
        }
    }

    // ---- Epilogue: logit[m] = sigmoid( sum_cols relu(acc + b1)*v + c ) ----
    float bb[8], vv[8];
#pragma unroll
    for (int ni = 0; ni < 8; ni++) {
        int col = wn * 128 + ni * 16 + l15;
        bb[ni] = b1[col];
        vv[ni] = v[col];
    }
    const float cconst = v[512];

    float* part = (float*)smem;      // [160][4] per-row partials per wn (aliases As)

#pragma unroll
    for (int mi = 0; mi < 5; mi++) {
#pragma unroll
        for (int r = 0; r < 4; r++) {
            float s = 0.f;
#pragma unroll
            for (int ni = 0; ni < 8; ni++)
                s += fmaxf(acc[mi][ni][r] + bb[ni], 0.f) * vv[ni];
            s += __shfl_xor(s, 1);
            s += __shfl_xor(s, 2);
            s += __shfl_xor(s, 4);
            s += __shfl_xor(s, 8);
            if (l15 == 0) {
                int row = wm * 80 + mi * 16 + q * 4 + r;
                part[row * 4 + wn] = s;
            }
        }
    }
    __syncthreads();
    if (t < mrows) {                             // only live rows stored
        float s = part[t * 4] + part[t * 4 + 1] + part[t * 4 + 2] + part[t * 4 + 3] + cconst;
        logits[m0 + t] = 1.f / (1.f + __expf(-s));
    }

    // ---- completion protocol (row-count): last block runs the top-k ----
    const int L = seq_len[bsmp];

    float* vals  = (float*)smem;                 // [2048]
    int*   redi  = (int*)(vals + 2048);          // [2][8] round-alternating
    unsigned* mnx = (unsigned*)(redi + 16);      // [16] min/max scratch
    float* redf  = (float*)(mnx + 16);           // [8]
    int*   wflag = (int*)(redf + 8);

    __syncthreads();                             // logits stores done block-wide
    if (t == 0) {
        __threadfence();                         // release: publish logits
        int old = atomicAdd(&done[bsmp], mrows);
        int win = (old + mrows == L);            // exactly one block sums to L
        if (win) __threadfence();                // acquire: see others' logits
        *wflag = win;
    }
    __syncthreads();
    if (!*wflag) return;

    // ---- exact top-k mean for sample bsmp (k = L/16 + 1) ----
    const int kk = (L >> 4) + 1;
    const float* p = logits + bsmp * T_SEQ;

    // stage + min/max in one pass (uint order == float order: all in (0,1))
    unsigned mn = 0x3f800000u, mx = 0u;          // 1.0f > all, 0 < all
    for (int i = t; i < L; i += 512) {
        float x = p[i];
        vals[i] = x;
        unsigned u = __float_as_uint(x);
        mn = min(mn, u); mx = max(mx, u);
    }
#pragma unroll
    for (int m = 32; m >= 1; m >>= 1) {
        mn = min(mn, (unsigned)__shfl_xor((int)mn, m));
        mx = max(mx, (unsigned)__shfl_xor((int)mx, m));
    }
    if (lane == 0) { mnx[wave] = mn; mnx[8 + wave] = mx; }
    __syncthreads();
    unsigned lo = mnx[0], hi = mnx[8];
#pragma unroll
    for (int w8 = 1; w8 < 8; w8++) {
        lo = min(lo, mnx[w8]); hi = max(hi, mnx[8 + w8]);
    }
    __syncthreads();    // mnx reads done before redi[0] writes

    // 2-probe bisection on float bits: ~log3 rounds, 1 barrier each.
    // Invariant: count(>= float(lo)) >= kk.
    int rb = 0;
    while (lo < hi) {
        unsigned wd = hi - lo;
        unsigned t1 = wd / 3u + 1u;
        unsigned m1 = lo + t1;                   // lo < m1 <= hi
        unsigned m2 = lo + (wd - wd / 3u);       // m1 <= m2 <= hi
        if (m2 < m1) m2 = m1;
        float f1 = __uint_as_float(m1), f2 = __uint_as_float(m2);
        int c1 = 0, c2 = 0;
        for (int i = t; i < L; i += 512) {
            float x = vals[i];
            c1 += (x >= f1) ? 1 : 0;
            c2 += (x >= f2) ? 1 : 0;
        }
        int packed = (c1 << 12) | c2;            // counts <= 2048 < 4096 each
#pragma unroll
        for (int m = 32; m >= 1; m >>= 1) packed += __shfl_xor(packed, m);
        if (lane == 0) redi[(rb & 1) * 8 + wave] = packed;
        __syncthreads();
        int tot = 0;
#pragma unroll
        for (int w8 = 0; w8 < 8; w8++) tot += redi[(rb & 1) * 8 + w8];
        int C2 = tot & 0xFFF, C1 = tot >> 12;
        if (C2 >= kk)      { lo = m2; }
        else if (C1 >= kk) { lo = m1; hi = m2 - 1; }
        else               { hi = m1 - 1; }
        rb++;
        // no extra barrier: next round writes the OTHER redi buffer
    }
    const float thr = __uint_as_float(lo);       // exact k-th largest value

    int cg = 0; float sg = 0.f;
    for (int i = t; i < L; i += 512) {
        float x = vals[i];
        if (x > thr) { cg += 1; sg += x; }
    }
#pragma unroll
    for (int m = 32; m >= 1; m >>= 1) {
        cg += __shfl_xor(cg, m);
        sg += __shfl_xor(sg, m);
    }
    if (lane == 0) { redi[(rb & 1) * 8 + wave] = cg; redf[wave] = sg; }
    __syncthreads();
    if (t == 0) {
        int cgt = 0; float sgt = 0.f;
#pragma unroll
        for (int w8 = 0; w8 < 8; w8++) { cgt += redi[(rb & 1) * 8 + w8]; sgt += redf[w8]; }
        out[bsmp] = (sgt + (float)(kk - cgt) * thr) / (float)kk;
    }
}

// ---------------------------------------------------------------------------
extern "C" void kernel_launch(void* const* d_in, const int* in_sizes, int n_in,
                              void* d_out, int out_size, void* d_ws, size_t ws_size,
                              hipStream_t stream) {
    const float* avf = (const float*)d_in[0];
    const float* W1  = (const float*)d_in[1];
    const float* b1  = (const float*)d_in[2];
    const float* W2  = (const float*)d_in[3];
    const float* b2  = (const float*)d_in[4];
    const float* W3  = (const float*)d_in[5];
    const float* b3  = (const float*)d_in[6];
    const int* seq_len = (const int*)d_in[7];
    float* out = (float*)d_out;

    char* ws = (char*)d_ws;
    bf16*  W1T    = (bf16*)ws;                          // 1 MB
    float* v      = (float*)(ws + (1 << 20));           // 513 floats
    int*   tiles  = (int*)(ws + (1 << 20) + 4096);      // 1 + up to 416 ints
    int*   done   = (int*)(ws + (1 << 20) + 8192);      // 32 ints
    float* logits = (float*)(ws + (1 << 20) + 12288);   // 256 KB

    transpose_prep<<<dim3(32, 16), 256, 0, stream>>>(W1, W1T, W2, b2, W3, b3,
                                                     seq_len, v, tiles, done);
    gemm_fused<<<NB * MAX_J, 512, 0, stream>>>(avf, W1T, b1, v, tiles, seq_len,
                                               done, logits, out);
}

// Round 5
// 394.731 us; speedup vs baseline: 1.1672x; 1.1672x over previous
//
#include <hip/hip_runtime.h>

typedef __bf16 bf16;
typedef __bf16 bf16x4 __attribute__((ext_vector_type(4)));
typedef __bf16 bf16x8 __attribute__((ext_vector_type(8)));
typedef float f32x4 __attribute__((ext_vector_type(4)));

#define K_TOT 1024    // D_IN
#define N_TOT 512     // H1
#define T_SEQ 2048
#define NB 32
#define M_TILE 160    // max rows per gemm block (LDS/acc capacity)
#define MAX_J 13      // ceil(2048/160): worst-case tiles/sample at fallback R=160
#define NBLK_TGT 256  // one block per CU -> single dispatch round

// ---------------------------------------------------------------------------
// async global->LDS, 16B per lane. LDS dest = wave-uniform base + lane*16.
// ---------------------------------------------------------------------------
__device__ __forceinline__ void async16(const void* g, void* l) {
    __builtin_amdgcn_global_load_lds(
        (const __attribute__((address_space(1))) unsigned int*)g,
        (__attribute__((address_space(3))) unsigned int*)l, 16, 0, 0);
}

// ---------------------------------------------------------------------------
// Kernel 0 (merged): W1 [1024,512] fp32 -> W1T [512,1024] bf16, AND (block 0)
// prep: fold layers 2+3 into v[], zero completion counters, and build a
// BALANCED block partition. PARALLEL partition solve (R4's serial greedy with
// ~1100 runtime int divides on ONE lane cost ~50 us and gated the gemm):
// feasibility of rows/block cap R is monotone, so thread R computes
// S(R) = sum_b ceil(L_b/R) in parallel; R* = min{R : S(R) <= 256} via LDS
// atomicMin. nb_b = ceil(L_b/R*), balanced split inside each sample.
// tiles[0] = total blocks; tiles[1+i] = (b<<19) | (start<<8) | nrows.
// ---------------------------------------------------------------------------
__global__ __launch_bounds__(256) void transpose_prep(
        const float* __restrict__ W1, bf16* __restrict__ W1T,
        const float* __restrict__ W2, const float* __restrict__ b2,
        const float* __restrict__ W3, const float* __restrict__ b3,
        const int* __restrict__ seq_len,
        float* __restrict__ v, int* __restrict__ tiles, int* __restrict__ done) {
    __shared__ float tile[32][33];
    const int t = threadIdx.x;
    const int k0 = blockIdx.x * 32;
    const int n0 = blockIdx.y * 32;
#pragma unroll
    for (int p = 0; p < 4; p++) {
        int kl = p * 8 + (t >> 5);
        int nl = t & 31;
        tile[kl][nl] = W1[(k0 + kl) * 512 + n0 + nl];
    }
    __syncthreads();
#pragma unroll
    for (int p = 0; p < 4; p++) {
        int nl = p * 8 + (t >> 5);
        int kl = t & 31;
        W1T[(n0 + nl) * 1024 + k0 + kl] = (bf16)tile[kl][nl];
    }

    if (blockIdx.x == 0 && blockIdx.y == 0) {   // block-uniform branch
        __shared__ int Ls[32], nb2[32], off2[32], rbest;
        // v[h] = sum_c W2[h][c]*W3[c];  v[512] = b2.W3 + b3
        for (int h = t; h < 512; h += 256) {
            float s = 0.f;
#pragma unroll
            for (int c = 0; c < 32; c++) s += W2[h * 32 + c] * W3[c];
            v[h] = s;
        }
        if (t == 0) {
            float cc = b3[0];
            for (int c = 0; c < 32; c++) cc += b2[c] * W3[c];
            v[512] = cc;
            rbest = M_TILE;                      // fallback: R=160 (may be >256 blocks)
        }
        if (t < 32) {
            Ls[t] = seq_len[t];
            done[t] = 0;                         // completion counters (rows)
        }
        __syncthreads();
        // parallel feasibility scan: thread t tests cap R = t+1 (R in [1,160])
        if (t < M_TILE) {
            int R = t + 1, S = 0;
#pragma unroll 4
            for (int i = 0; i < 32; i++) S += (Ls[i] + R - 1) / R;
            if (S <= NBLK_TGT) atomicMin(&rbest, R);
        }
        __syncthreads();
        const int R = rbest;
        if (t < 32) nb2[t] = (Ls[t] + R - 1) / R;   // blocks for sample t
        __syncthreads();
        if (t == 0) {
            int a = 0;
            for (int i = 0; i < 32; i++) { off2[i] = a; a += nb2[i]; }
            tiles[0] = a;
        }
        __syncthreads();
        for (int idx = t; idx < 32 * 256; idx += 256) {
            int b = idx >> 8, j = idx & 255;
            int nb = nb2[b];
            if (j < nb) {
                int L = Ls[b];
                int q = L / nb, r = L % nb;       // balanced split, all >= 1
                int start = j * q + (j < r ? j : r);
                int nrows = q + (j < r ? 1 : 0);
                tiles[1 + off2[b] + j] = (b << 19) | (start << 8) | nrows;
            }
        }
    }
}

// ---------------------------------------------------------------------------
// Kernel 1 (fused gemm + MLP epilogue + per-sample top-k):
// per block: mrows (<=160) rows x full N=512; logits = sigmoid(sum relu*v+c).
// LDS 148 KB: A single-buffered 20 KB + B double-buffered 2x64 KB
// (global_load_lds). Dead rows (>= mrows): A-load/store predicated off AND
// the MFMA mi-cluster skipped (wave-uniform branch: wm & mrows uniform) --
// the 2 waves/SIMD share the matrix pipe, so skipped MFMAs free issue slots
// for the co-resident full wave; compute now scales with mrows.
// Last block of each sample (row-count protocol) runs its top-k mean inline.
// ---------------------------------------------------------------------------
__device__ __forceinline__ int sw_idx(int row, int e) {  // elem idx into [row][64]
    return row * 64 + (((e >> 3) ^ (row & 7)) << 3) + (e & 7);
}

__global__ __launch_bounds__(512, 2) void gemm_fused(const float* __restrict__ A,
                                                     const bf16* __restrict__ W1T,
                                                     const float* __restrict__ b1,
                                                     const float* __restrict__ v,
                                                     const int* __restrict__ tiles,
                                                     const int* __restrict__ seq_len,
                                                     int* __restrict__ done,
                                                     float* __restrict__ logits,
                                                     float* __restrict__ out) {
    // 160*64 (A) + 2 * 512*64 (B) bf16 = 148 KB
    __shared__ bf16 smem[M_TILE * 64 + 2 * N_TOT * 64];
    bf16* As = smem;
    bf16* Bs0 = smem + M_TILE * 64;
    bf16* Bs1 = Bs0 + N_TOT * 64;

    const int nact = tiles[0];
    if ((int)blockIdx.x >= nact) return;         // dead slot
    const int w = tiles[1 + blockIdx.x];
    const int bsmp = w >> 19;                    // owning sample
    const int start = (w >> 8) & 0x7FF;          // first row within sample
    const int mrows = w & 0xFF;                  // live rows this block (<=160)
    const int m0 = bsmp * T_SEQ + start;         // first global row

    const int t = threadIdx.x;
    const int wave = t >> 6, lane = t & 63;
    const int q = lane >> 4, l15 = lane & 15;
    const int wm = wave >> 2, wn = wave & 3;     // 2 x 4 wave grid; wm tile 80 rows

    // A staging: thread t handles float4 col c16 = t&15 of rows r0+p*32.
    const int c16 = t & 15, r0 = t >> 4;
    bool alive[5];                               // staging-row liveness
    const float* agp[5];
#pragma unroll
    for (int p = 0; p < 5; p++) {
        alive[p] = (r0 + p * 32) < mrows;
        agp[p] = A + (size_t)(m0 + r0 + p * 32) * K_TOT + c16 * 4;  // deref'd only if live
    }
    bool mlive[5];                               // MFMA mi-cluster liveness (wave-uniform)
#pragma unroll
    for (int p = 0; p < 5; p++) mlive[p] = (wm * 80 + p * 16) < mrows;

    // B async staging: lane -> n-row wave*64 + (lane>>3), global 16B chunk
    // XOR-permuted so linear LDS (base + lane*16) ends up swizzled.
    const int bl_row = wave * 64 + (lane >> 3);
    const int bl_chunk = (lane & 7) ^ ((lane >> 3) & 7);
    const bf16* bgp = W1T + (size_t)bl_row * K_TOT + bl_chunk * 8;

    f32x4 acc[5][8] = {};
    float4 av[5];

    auto loadA = [&](int k0) {
#pragma unroll
        for (int p = 0; p < 5; p++)
            if (alive[p]) av[p] = *(const float4*)(agp[p] + k0);
    };
    auto asyncB = [&](int k0, bf16* bs) {
#pragma unroll
        for (int j = 0; j < 8; j++)
            async16(bgp + k0 + (size_t)j * 8 * K_TOT, bs + (wave * 64 + j * 8) * 64);
    };
    auto writeA = [&]() {
#pragma unroll
        for (int p = 0; p < 5; p++) {
            if (!alive[p]) continue;
            bf16x4 wv;
            wv[0] = (bf16)av[p].x; wv[1] = (bf16)av[p].y;
            wv[2] = (bf16)av[p].z; wv[3] = (bf16)av[p].w;
            int row = r0 + p * 32;
            int chunk = c16 >> 1;                 // global 8-elem chunk
            int idx = row * 64 + ((chunk ^ (row & 7)) << 3) + (c16 & 1) * 4;
            *(bf16x4*)(&As[idx]) = wv;
        }
    };
    auto mfma_phase = [&](const bf16* bs) {
#pragma unroll
        for (int kk = 0; kk < 64; kk += 32) {
            const int e = kk + q * 8;
            bf16x8 af[5];
#pragma unroll
            for (int mi = 0; mi < 5; mi++)
                if (mlive[mi])
                    af[mi] = *(const bf16x8*)(&As[sw_idx(wm * 80 + mi * 16 + l15, e)]);
#pragma unroll
            for (int nh = 0; nh < 8; nh += 4) {   // ni-halves: caps VGPR pressure
                bf16x8 bfv[4];
#pragma unroll
                for (int ni = 0; ni < 4; ni++)
                    bfv[ni] = *(const bf16x8*)(&bs[sw_idx(wn * 128 + (nh + ni) * 16 + l15, e)]);
#pragma unroll
                for (int mi = 0; mi < 5; mi++)
                    if (mlive[mi])
#pragma unroll
                        for (int ni = 0; ni < 4; ni++)
                            acc[mi][nh + ni] = __builtin_amdgcn_mfma_f32_16x16x32_bf16(
                                af[mi], bfv[ni], acc[mi][nh + ni], 0, 0, 0);
            }
        }
    };

    // ---- preload k=0 ----
    loadA(0);
    asyncB(0, Bs0);
    writeA();           // compiler: vmcnt -> waits A only, B stays in flight
    __syncthreads();    // drains B(0); A(0) visible

#pragma unroll 1
    for (int k = 0; k < 16; k++) {
        bf16* bcur = (k & 1) ? Bs1 : Bs0;
        bf16* bnxt = (k & 1) ? Bs0 : Bs1;
        if (k < 15) {
            loadA((k + 1) * 64);        // A(k+1) -> VGPR (overlaps MFMA below)
            asyncB((k + 1) * 64, bnxt); // B(k+1) -> LDS async
        }
        mfma_phase(bcur);               // covers load latency
        __syncthreads();                // waves done reading As/B(k); drains B(k+1)
        if (k < 15) {
            writeA();                   // overwrite single A buffer with A(k+1)
            __syncthreads();            // A(k+1) visible
        }
    }

    // ---- Epilogue: logit[m] = sigmoid( sum_cols relu(acc + b1)*v + c ) ----
    float bb[8], vv[8];
#pragma unroll
    for (int ni = 0; ni < 8; ni++) {
        int col = wn * 128 + ni * 16 + l15;
        bb[ni] = b1[col];
        vv[ni] = v[col];
    }
    const float cconst = v[512];

    float* part = (float*)smem;      // [160][4] per-row partials per wn (aliases As)

#pragma unroll
    for (int mi = 0; mi < 5; mi++) {
#pragma unroll
        for (int r = 0; r < 4; r++) {
            float s = 0.f;
#pragma unroll
            for (int ni = 0; ni < 8; ni++)
                s += fmaxf(acc[mi][ni][r] + bb[ni], 0.f) * vv[ni];
            s += __shfl_xor(s, 1);
            s += __shfl_xor(s, 2);
            s += __shfl_xor(s, 4);
            s += __shfl_xor(s, 8);
            if (l15 == 0) {
                int row = wm * 80 + mi * 16 + q * 4 + r;
                part[row * 4 + wn] = s;
            }
        }
    }
    __syncthreads();
    if (t < mrows) {                             // only live rows stored
        float s = part[t * 4] + part[t * 4 + 1] + part[t * 4 + 2] + part[t * 4 + 3] + cconst;
        logits[m0 + t] = 1.f / (1.f + __expf(-s));
    }

    // ---- completion protocol (row-count): last block runs the top-k ----
    const int L = seq_len[bsmp];

    float* vals  = (float*)smem;                 // [2048]
    int*   redi  = (int*)(vals + 2048);          // [2][8] round-alternating
    unsigned* mnx = (unsigned*)(redi + 16);      // [16] min/max scratch
    float* redf  = (float*)(mnx + 16);           // [8]
    int*   wflag = (int*)(redf + 8);

    __syncthreads();                             // logits stores done block-wide
    if (t == 0) {
        __threadfence();                         // release: publish logits
        int old = atomicAdd(&done[bsmp], mrows);
        int win = (old + mrows == L);            // exactly one block sums to L
        if (win) __threadfence();                // acquire: see others' logits
        *wflag = win;
    }
    __syncthreads();
    if (!*wflag) return;

    // ---- exact top-k mean for sample bsmp (k = L/16 + 1) ----
    const int kk = (L >> 4) + 1;
    const float* p = logits + bsmp * T_SEQ;

    // stage + min/max in one pass (uint order == float order: all in (0,1))
    unsigned mn = 0x3f800000u, mx = 0u;          // 1.0f > all, 0 < all
    for (int i = t; i < L; i += 512) {
        float x = p[i];
        vals[i] = x;
        unsigned u = __float_as_uint(x);
        mn = min(mn, u); mx = max(mx, u);
    }
#pragma unroll
    for (int m = 32; m >= 1; m >>= 1) {
        mn = min(mn, (unsigned)__shfl_xor((int)mn, m));
        mx = max(mx, (unsigned)__shfl_xor((int)mx, m));
    }
    if (lane == 0) { mnx[wave] = mn; mnx[8 + wave] = mx; }
    __syncthreads();
    unsigned lo = mnx[0], hi = mnx[8];
#pragma unroll
    for (int w8 = 1; w8 < 8; w8++) {
        lo = min(lo, mnx[w8]); hi = max(hi, mnx[8 + w8]);
    }
    __syncthreads();    // mnx reads done before redi[0] writes

    // 2-probe bisection on float bits: ~log3 rounds, 1 barrier each.
    // Invariant: count(>= float(lo)) >= kk.
    int rb = 0;
    while (lo < hi) {
        unsigned wd = hi - lo;
        unsigned t1 = wd / 3u + 1u;
        unsigned m1 = lo + t1;                   // lo < m1 <= hi
        unsigned m2 = lo + (wd - wd / 3u);       // m1 <= m2 <= hi
        if (m2 < m1) m2 = m1;
        float f1 = __uint_as_float(m1), f2 = __uint_as_float(m2);
        int c1 = 0, c2 = 0;
        for (int i = t; i < L; i += 512) {
            float x = vals[i];
            c1 += (x >= f1) ? 1 : 0;
            c2 += (x >= f2) ? 1 : 0;
        }
        int packed = (c1 << 12) | c2;            // counts <= 2048 < 4096 each
#pragma unroll
        for (int m = 32; m >= 1; m >>= 1) packed += __shfl_xor(packed, m);
        if (lane == 0) redi[(rb & 1) * 8 + wave] = packed;
        __syncthreads();
        int tot = 0;
#pragma unroll
        for (int w8 = 0; w8 < 8; w8++) tot += redi[(rb & 1) * 8 + w8];
        int C2 = tot & 0xFFF, C1 = tot >> 12;
        if (C2 >= kk)      { lo = m2; }
        else if (C1 >= kk) { lo = m1; hi = m2 - 1; }
        else               { hi = m1 - 1; }
        rb++;
        // no extra barrier: next round writes the OTHER redi buffer
    }
    const float thr = __uint_as_float(lo);       // exact k-th largest value

    int cg = 0; float sg = 0.f;
    for (int i = t; i < L; i += 512) {
        float x = vals[i];
        if (x > thr) { cg += 1; sg += x; }
    }
#pragma unroll
    for (int m = 32; m >= 1; m >>= 1) {
        cg += __shfl_xor(cg, m);
        sg += __shfl_xor(sg, m);
    }
    if (lane == 0) { redi[(rb & 1) * 8 + wave] = cg; redf[wave] = sg; }
    __syncthreads();
    if (t == 0) {
        int cgt = 0; float sgt = 0.f;
#pragma unroll
        for (int w8 = 0; w8 < 8; w8++) { cgt += redi[(rb & 1) * 8 + w8]; sgt += redf[w8]; }
        out[bsmp] = (sgt + (float)(kk - cgt) * thr) / (float)kk;
    }
}

// ---------------------------------------------------------------------------
extern "C" void kernel_launch(void* const* d_in, const int* in_sizes, int n_in,
                              void* d_out, int out_size, void* d_ws, size_t ws_size,
                              hipStream_t stream) {
    const float* avf = (const float*)d_in[0];
    const float* W1  = (const float*)d_in[1];
    const float* b1  = (const float*)d_in[2];
    const float* W2  = (const float*)d_in[3];
    const float* b2  = (const float*)d_in[4];
    const float* W3  = (const float*)d_in[5];
    const float* b3  = (const float*)d_in[6];
    const int* seq_len = (const int*)d_in[7];
    float* out = (float*)d_out;

    char* ws = (char*)d_ws;
    bf16*  W1T    = (bf16*)ws;                          // 1 MB
    float* v      = (float*)(ws + (1 << 20));           // 513 floats
    int*   tiles  = (int*)(ws + (1 << 20) + 4096);      // 1 + up to 416 ints
    int*   done   = (int*)(ws + (1 << 20) + 8192);      // 32 ints
    float* logits = (float*)(ws + (1 << 20) + 12288);   // 256 KB

    transpose_prep<<<dim3(32, 16), 256, 0, stream>>>(W1, W1T, W2, b2, W3, b3,
                                                     seq_len, v, tiles, done);
    gemm_fused<<<NB * MAX_J, 512, 0, stream>>>(avf, W1T, b1, v, tiles, seq_len,
                                               done, logits, out);
}